// Round 7
// baseline (32.522 us; speedup 1.0000x reference)
//
#include <hip/hip_runtime.h>
#include <hip/hip_bf16.h>

// FSMN: strided dilated depthwise conv over time + residual.
// R5 finding: 25.5us vs ~16.5us HBM floor; occupancy 50%, VALUBusy 23% —
// issue/latency-limited with scalar (4B/lane) accesses.
// R6 fix: float2 per thread + S=10 flat window. Needed span for 10 outputs is
// exactly [t0-20, t0+18] = 39 slots -> load the whole window upfront (39
// independent float2 loads = 19.5KB in flight/wave), then 5 double-steps of
// static-index FMA, then 10 nt float2 stores. No ring/modulo/prefetch logic.
// R6b: __builtin_nontemporal_store needs a clang native vector type, not
// HIP_vector_type -> use ext_vector_type(2) float.

typedef float f32x2 __attribute__((ext_vector_type(2)));

constexpr int B = 16;
constexpr int T = 2000;
constexpr int D = 512;
constexpr int D2 = D / 2;          // 256 float2 per (b,t) row
constexpr int NTAP = 16;           // filt rows: 0..9 left, 10 center, 11..15 right
constexpr int S = 10;              // outputs per thread strip
constexpr int NSTRIP = T / S;      // 200
constexpr int ITERS = S / 2;       // 5 double-steps
constexpr int WSPAN = 39;          // slots [t0-20 .. t0+18]
constexpr int NXCD = 8;

__global__ __launch_bounds__(256, 4) void fsmn_f2_kernel(
    const f32x2* __restrict__ x,      // (B,T,D2)
    const f32x2* __restrict__ filt,   // (16,D2)
    f32x2* __restrict__ out)          // (B,T,D2)
{
    // grid = B*NSTRIP = 3200 blocks; bid -> (b, strip), strip fastest so
    // adjacent strips (sharing halo rows) land on the same XCD chunk.
    const int nbl = B * NSTRIP;              // 3200
    const int cpx = nbl / NXCD;              // 400
    int bid = blockIdx.x;
    bid = (bid & (NXCD - 1)) * cpx + (bid >> 3);   // chunked XCD swizzle

    const int strip = bid % NSTRIP;
    const int b     = bid / NSTRIP;
    const int d2    = (int)threadIdx.x;      // float2 column, 0..255
    const int t0    = strip * S;
    const int rowbase = b * T;

    // filter taps for this d-pair, residual folded into center tap
    f32x2 F[NTAP];
#pragma unroll
    for (int k = 0; k < NTAP; ++k) F[k] = filt[k * D2 + d2];
    F[10].x += 1.0f;
    F[10].y += 1.0f;

    // flat window: W[m] = x[b, t0-20+m, d-pair], zero outside [0,T)
    f32x2 W[WSPAN];
#pragma unroll
    for (int m = 0; m < WSPAN; ++m) {
        const int p = t0 - 20 + m;
        if (p >= 0 && p < T) {
            W[m] = x[(rowbase + p) * D2 + d2];
        } else {
            W[m] = (f32x2)(0.0f);
        }
    }

    f32x2* op = out + (size_t)(rowbase + t0) * D2 + d2;

#pragma unroll
    for (int i = 0; i < ITERS; ++i) {
        const int s0 = 2 * i;   // slot of (t-20) for even output t = t0+2i
        f32x2 a0, a1;
        a0.x = W[s0].x * F[0].x;         a0.y = W[s0].y * F[0].y;
        a1.x = W[s0 + 1].x * F[0].x;     a1.y = W[s0 + 1].y * F[0].y;

        // left taps k=1..9 (slot s0+2k) and center k=10 (slot s0+20, +1 folded)
#pragma unroll
        for (int k = 1; k <= 10; ++k) {
            a0.x = fmaf(W[s0 + 2 * k].x,     F[k].x, a0.x);
            a0.y = fmaf(W[s0 + 2 * k].y,     F[k].y, a0.y);
            a1.x = fmaf(W[s0 + 2 * k + 1].x, F[k].x, a1.x);
            a1.y = fmaf(W[s0 + 2 * k + 1].y, F[k].y, a1.y);
        }
        // right taps k=0..4 -> filt[11+k], slot s0+21+2k
#pragma unroll
        for (int k = 0; k <= 4; ++k) {
            a0.x = fmaf(W[s0 + 21 + 2 * k].x, F[11 + k].x, a0.x);
            a0.y = fmaf(W[s0 + 21 + 2 * k].y, F[11 + k].y, a0.y);
            a1.x = fmaf(W[s0 + 22 + 2 * k].x, F[11 + k].x, a1.x);
            a1.y = fmaf(W[s0 + 22 + 2 * k].y, F[11 + k].y, a1.y);
        }

        // nontemporal: output is never re-read — keep L2/L3 for input reuse
        __builtin_nontemporal_store(a0, &op[(2 * i) * D2]);
        __builtin_nontemporal_store(a1, &op[(2 * i + 1) * D2]);
    }
}

extern "C" void kernel_launch(void* const* d_in, const int* in_sizes, int n_in,
                              void* d_out, int out_size, void* d_ws, size_t ws_size,
                              hipStream_t stream) {
    const f32x2* x    = (const f32x2*)d_in[0];
    const f32x2* filt = (const f32x2*)d_in[1];
    f32x2* out        = (f32x2*)d_out;

    const int grid = B * NSTRIP;   // 3200 blocks, /8 XCDs evenly
    fsmn_f2_kernel<<<grid, 256, 0, stream>>>(x, filt, out);
}

// Round 8
// 27.843 us; speedup vs baseline: 1.1680x; 1.1680x over previous
//
#include <hip/hip_runtime.h>
#include <hip/hip_bf16.h>

// FSMN: strided dilated depthwise conv over time + residual.
// R7 finding: compiler sinks "upfront" register-window loads next to uses
// (VGPR 60 not ~120) -> serialized chains, MLP lost, 32.5us.
// R8 fix: LDS staging via global_load_lds (fire-and-forget, no VGPR cost,
// drained once at the barrier). Block = (b, d-half, S=10 strip): stage 39 rows
// x 1KB into LDS (each wave issues ~10 independent 1KB direct-to-LDS loads),
// barrier, then per-thread column sliding window from LDS: 39 ds_read_b32,
// 160 FMA, 10 nt stores. 39KB LDS -> 4 blocks/CU.

typedef float f32x4 __attribute__((ext_vector_type(4)));
typedef __attribute__((address_space(1))) const unsigned int gas_u32;
typedef __attribute__((address_space(3))) unsigned int las_u32;

constexpr int B = 16;
constexpr int T = 2000;
constexpr int D = 512;
constexpr int DH = 256;            // columns per block (half of D)
constexpr int NTAP = 16;           // filt rows: 0..9 left, 10 center, 11..15 right
constexpr int S = 10;              // output rows per block
constexpr int NSTRIP = T / S;      // 200
constexpr int WROWS = 39;          // staged rows [t0-20 .. t0+18]
constexpr int NXCD = 8;

__global__ __launch_bounds__(256) void fsmn_lds_kernel(
    const float* __restrict__ x,      // (B,T,D)
    const float* __restrict__ filt,   // (16,D)
    float* __restrict__ out)          // (B,T,D)
{
    __shared__ float smem[WROWS * DH];   // 39 KB

    // grid = B*2*NSTRIP = 6400; bid -> (b, dhalf, strip), strip fastest so
    // neighbor strips (sharing the 29-row halo) land on the same XCD chunk.
    const int nbl = B * 2 * NSTRIP;          // 6400
    const int cpx = nbl / NXCD;              // 800
    int bid = blockIdx.x;
    bid = (bid & (NXCD - 1)) * cpx + (bid >> 3);   // chunked XCD swizzle

    const int strip = bid % NSTRIP;
    const int bh    = bid / NSTRIP;          // 0..31
    const int dhalf = bh & 1;
    const int b     = bh >> 1;
    const int t0    = strip * S;

    const int tid  = (int)threadIdx.x;
    const int wave = tid >> 6;
    const int lane = tid & 63;

    // ---- stage window rows into LDS (wave w does rows m = w, w+4, ...) ----
    // row m holds x[b, t0-20+m, dhalf*256 .. dhalf*256+255]
    const float* gx = x + (size_t)(b * T) * D + dhalf * DH;
#pragma unroll
    for (int j = 0; j < 10; ++j) {
        const int m = wave + 4 * j;
        if (m < WROWS) {                      // wave-uniform condition
            const int p = t0 - 20 + m;
            if (p >= 0 && p < T) {            // block-uniform-ish, scalar branch
                const float* src = gx + (size_t)p * D + lane * 4;  // 16B/lane
                __builtin_amdgcn_global_load_lds(
                    (gas_u32*)src,
                    (las_u32*)&smem[m * DH],  // wave-uniform base; HW adds lane*16
                    16, 0, 0);
            } else {
                // zero the out-of-range row: lane writes its 16B segment
                ((f32x4*)&smem[m * DH])[lane] = (f32x4)(0.0f);
            }
        }
    }

    // filter taps for this column — issued before the barrier so these global
    // loads overlap the staging drain; residual folded into center tap.
    const int c = tid;                        // 0..255
    float F[NTAP];
#pragma unroll
    for (int k = 0; k < NTAP; ++k) F[k] = filt[k * D + dhalf * DH + c];
    F[10] += 1.0f;

    __syncthreads();   // drains vmcnt (global_load_lds) + lgkmcnt (zero writes)

    // ---- per-thread sliding window over its column, entirely from LDS ----
    float W[WROWS];
#pragma unroll
    for (int m = 0; m < WROWS; ++m) W[m] = smem[m * DH + c];

    float* op = out + (size_t)(b * T + t0) * D + dhalf * DH + c;
#pragma unroll
    for (int i = 0; i < S; ++i) {
        // output t = t0+i needs window row m = i + off,
        // off: left 2k (k=0..9), center 20, right 21+2k (k=0..4)
        float a = W[i + 20] * F[10];
#pragma unroll
        for (int k = 0; k < 10; ++k) a = fmaf(W[i + 2 * k], F[k], a);
#pragma unroll
        for (int k = 0; k < 5; ++k)  a = fmaf(W[i + 21 + 2 * k], F[11 + k], a);
        // nontemporal: output never re-read — keep L2/L3 for the input halo
        __builtin_nontemporal_store(a, &op[(size_t)i * D]);
    }
}

extern "C" void kernel_launch(void* const* d_in, const int* in_sizes, int n_in,
                              void* d_out, int out_size, void* d_ws, size_t ws_size,
                              hipStream_t stream) {
    const float* x    = (const float*)d_in[0];
    const float* filt = (const float*)d_in[1];
    float* out        = (float*)d_out;

    const int grid = B * 2 * NSTRIP;   // 6400 blocks, /8 XCDs evenly
    fsmn_lds_kernel<<<grid, 256, 0, stream>>>(x, filt, out);
}